// Round 7
// baseline (809.564 us; speedup 1.0000x reference)
//
#include <hip/hip_runtime.h>
#include <cstdint>

#define DIMSZ 1024
#define NH 16
#define HDIM 64
#define TLEN 4096
#define BSZ 4
#define EPSF 1.1920928955078125e-07f

typedef __bf16 bf16x8 __attribute__((ext_vector_type(8)));
typedef float f32x4 __attribute__((ext_vector_type(4)));
typedef float f32x16 __attribute__((ext_vector_type(16)));
typedef uint16_t u16x8 __attribute__((ext_vector_type(8)));

__device__ __forceinline__ uint16_t f2bf(float f) {
  uint32_t u = __builtin_bit_cast(uint32_t, f);
  u += 0x7FFFu + ((u >> 16) & 1u);
  return (uint16_t)(u >> 16);
}
__device__ __forceinline__ float bf2f(uint16_t b) {
  return __builtin_bit_cast(float, ((uint32_t)b) << 16);
}

// async global->LDS, 16B per lane; LDS dest = wave-uniform base + lane*16
__device__ __forceinline__ void gl_lds16(const uint16_t* g, uint16_t* l) {
  __builtin_amdgcn_global_load_lds(
      (__attribute__((address_space(1))) uint32_t*)(g),
      (__attribute__((address_space(3))) uint32_t*)(l), 16, 0, 0);
}

// pack two f32 -> two bf16 in one u32 (low = a, high = b)
__device__ __forceinline__ uint32_t cvtpk(float a, float b) {
  uint32_t r;
  asm("v_cvt_pk_bf16_f32 %0, %1, %2" : "=v"(r) : "v"(a), "v"(b));
  return r;
}
// swap upper-32-lanes of a with lower-32-lanes of b (both updated).
// NOTE: operands must hold DISTINCT values (distinct live registers).
__device__ __forceinline__ void pls32(uint32_t& a, uint32_t& b) {
  asm("v_permlane32_swap_b32 %0, %1" : "+v"(a), "+v"(b));
}
// cross-half pair reductions via shfl (safe: compiler-generated)
__device__ __forceinline__ float pairmax32(float x) {
  return fmaxf(x, __shfl_xor(x, 32));
}

// ---------------- fp32 -> bf16 cast (8 elems/thread) ----------------
__global__ __launch_bounds__(256) void cvt_f32_bf16(const float* __restrict__ src,
                                                    uint16_t* __restrict__ dst, int n8) {
  int i = blockIdx.x * 256 + threadIdx.x;
  if (i >= n8) return;
  const float4* s4 = ((const float4*)src) + (size_t)i * 2;
  float4 a = s4[0], b = s4[1];
  u16x8 o;
  o[0] = f2bf(a.x); o[1] = f2bf(a.y); o[2] = f2bf(a.z); o[3] = f2bf(a.w);
  o[4] = f2bf(b.x); o[5] = f2bf(b.y); o[6] = f2bf(b.z); o[7] = f2bf(b.w);
  *(((u16x8*)dst) + i) = o;
}

// ---------------- bf16 GEMM, C = A * W^T  (both row-major [.][K]) ----------------
template <int EPI>
__global__ __launch_bounds__(256) void gemm_bt(const uint16_t* __restrict__ A,
                                               const uint16_t* __restrict__ Bw,
                                               float* __restrict__ C,
                                               uint16_t* __restrict__ q_out,
                                               uint16_t* __restrict__ k_out,
                                               uint16_t* __restrict__ v_out,
                                               int M, int N, int K) {
  __shared__ uint16_t As[128 * 32];
  __shared__ uint16_t Bs[128 * 32];
  const int nb = blockIdx.x, mb = blockIdx.y;
  const int tid = threadIdx.x;
  const int wave = tid >> 6, lane = tid & 63;
  const int l15 = lane & 15, l4 = lane >> 4;
  const int wr = wave >> 1, wc = wave & 1;

  f32x4 acc[4][4];
  const f32x4 fz = {0.f, 0.f, 0.f, 0.f};
#pragma unroll
  for (int i = 0; i < 4; ++i)
#pragma unroll
    for (int j = 0; j < 4; ++j) acc[i][j] = fz;

  const uint16_t* Ab = A + (size_t)mb * 128 * K;
  const uint16_t* Bb = Bw + (size_t)nb * 128 * K;
  const int rA = wave * 32 + (lane >> 2);
  const int cA = (lane & 3) * 8;

  for (int k0 = 0; k0 < K; k0 += 32) {
    gl_lds16(Ab + (size_t)rA * K + k0 + cA, &As[(wave * 32) * 32]);
    gl_lds16(Ab + (size_t)(rA + 16) * K + k0 + cA, &As[(wave * 32 + 16) * 32]);
    gl_lds16(Bb + (size_t)rA * K + k0 + cA, &Bs[(wave * 32) * 32]);
    gl_lds16(Bb + (size_t)(rA + 16) * K + k0 + cA, &Bs[(wave * 32 + 16) * 32]);
    __syncthreads();
    bf16x8 af[4], bfr[4];
#pragma unroll
    for (int i = 0; i < 4; ++i)
      af[i] = *(const bf16x8*)&As[(wr * 64 + i * 16 + l15) * 32 + l4 * 8];
#pragma unroll
    for (int j = 0; j < 4; ++j)
      bfr[j] = *(const bf16x8*)&Bs[(wc * 64 + j * 16 + l15) * 32 + l4 * 8];
#pragma unroll
    for (int i = 0; i < 4; ++i)
#pragma unroll
      for (int j = 0; j < 4; ++j)
        acc[i][j] = __builtin_amdgcn_mfma_f32_16x16x32_bf16(af[i], bfr[j], acc[i][j], 0, 0, 0);
    __syncthreads();
  }

  const int mrow = mb * 128 + wr * 64;
  const int ncol = nb * 128 + wc * 64;
  if (EPI == 0) {
#pragma unroll
    for (int i = 0; i < 4; ++i)
#pragma unroll
      for (int j = 0; j < 4; ++j) {
        int n = ncol + j * 16 + l15;
#pragma unroll
        for (int r = 0; r < 4; ++r) {
          int m = mrow + i * 16 + l4 * 4 + r;
          C[(size_t)m * N + n] = acc[i][j][r];
        }
      }
  } else {
#pragma unroll
    for (int i = 0; i < 4; ++i)
#pragma unroll
      for (int j = 0; j < 4; ++j) {
        int n = ncol + j * 16 + l15;
        int tens = n >> 10;
        int h = (n >> 6) & (NH - 1);
        int d = n & (HDIM - 1);
        uint16_t* dst = (tens == 0) ? q_out : ((tens == 1) ? k_out : v_out);
#pragma unroll
        for (int r = 0; r < 4; ++r) {
          int m = mrow + i * 16 + l4 * 4 + r;
          int b = m >> 12, t = m & (TLEN - 1);
          dst[((((size_t)b * NH + h) * TLEN) + t) * HDIM + d] = f2bf(acc[i][j][r]);
        }
      }
  }
}

// ---------------- RoPE + RMS-norm, in place on q/k [B][H][T][64] ----------------
// q additionally scaled by 1/sqrt(HD)=0.125 (round-4 numerics)
__global__ __launch_bounds__(256) void rope_rms(uint16_t* __restrict__ qh,
                                                uint16_t* __restrict__ kh,
                                                const float* __restrict__ cosb,
                                                const float* __restrict__ sinb) {
  const int wid = blockIdx.x * 4 + (threadIdx.x >> 6);
  const int lane = threadIdx.x & 63;
  const int t = wid & (TLEN - 1);
  const int p = lane & 31;
  const float c = cosb[t * 32 + p];
  const float s = sinb[t * 32 + p];
  const size_t base = (size_t)wid * HDIM;
  {
    float v = bf2f(qh[base + lane]);
    float x1 = __shfl(v, p);
    float x2 = __shfl(v, p + 32);
    float rot = (lane < 32) ? (x1 * c + x2 * s) : (x2 * c - x1 * s);
    float ss = rot * rot;
#pragma unroll
    for (int off = 1; off < 64; off <<= 1) ss += __shfl_xor(ss, off);
    float sc = rsqrtf(ss * (1.0f / HDIM) + EPSF) * 0.125f;
    qh[base + lane] = f2bf(rot * sc);
  }
  {
    float v = bf2f(kh[base + lane]);
    float x1 = __shfl(v, p);
    float x2 = __shfl(v, p + 32);
    float rot = (lane < 32) ? (x1 * c + x2 * s) : (x2 * c - x1 * s);
    float ss = rot * rot;
#pragma unroll
    for (int off = 1; off < 64; off <<= 1) ss += __shfl_xor(ss, off);
    kh[base + lane] = f2bf(rot * rsqrtf(ss * (1.0f / HDIM) + EPSF));
  }
}

// ---------------- flash attention fwd ----------------
// Swapped QK^T (S^T = K Q^T), in-register online softmax (round-4 numerics:
// max-tracked with defer-max THR=8, __expf(s-m)). Single barrier per KV tile,
// double-buffered K (global_load_lds) and V (reg-staged transpose).
__global__ __launch_bounds__(256) void flash_attn(const uint16_t* __restrict__ qh,
                                                  const uint16_t* __restrict__ kh,
                                                  const uint16_t* __restrict__ vh,
                                                  uint16_t* __restrict__ yw) {
  __shared__ __align__(16) char smem[34816];
  // layout: K0 [0,8192) K1 [8192,16384) V0 [16384,25600) V1 [25600,34816)

  const int braw = blockIdx.x;
  const int bid = (braw & 7) * 256 + (braw >> 3);  // XCD swizzle (2048 % 8 == 0)
  const int qt = bid & 31;      // 32 q-tiles of 128
  const int bh = bid >> 5;      // b*NH + h
  const int tid = threadIdx.x;
  const int wave = tid >> 6, lane = tid & 63;
  const int q5 = lane & 31, hi = lane >> 5;

  // Q^T B-fragments in registers: lane holds Q[q5][ks*16 + hi*8 + 0..7]
  const uint16_t* qb = qh + ((size_t)bh * TLEN + qt * 128 + wave * 32) * HDIM;
  bf16x8 qf[4];
#pragma unroll
  for (int ks = 0; ks < 4; ++ks)
    qf[ks] = *(const bf16x8*)(qb + q5 * HDIM + ks * 16 + hi * 8);

  const uint16_t* kb = kh + (size_t)bh * TLEN * HDIM;
  const uint16_t* vb = vh + (size_t)bh * TLEN * HDIM;

  // K staging: wave stages rows [wave*16, +16), src chunk pre-swizzled
  const int krow = wave * 16 + (lane >> 3);
  const int kc8 = (lane & 7) ^ (krow & 7);
  const size_t koff = (size_t)krow * HDIM + kc8 * 8;
  const int kdst = wave * 16 * 64;

  // V staging: thread owns (row=tid&63, colblocks vc8 and vc8+32)
  const int vrow = tid & 63;
  const int vc8 = (tid >> 6) * 8;

  f32x16 accO[2];
  float m_run = -INFINITY, l_run = 0.f;
#pragma unroll
  for (int db = 0; db < 2; ++db)
#pragma unroll
    for (int r = 0; r < 16; ++r) accO[db][r] = 0.f;

  // ---- prologue: stage tile 0 into buffer 0 ----
  gl_lds16(kb + koff, (uint16_t*)smem + kdst);
  gl_lds16(kb + koff + 8 * HDIM, (uint16_t*)smem + kdst + 8 * 64);
  {
    const uint16_t* vsrc = vb + (size_t)vrow * HDIM + vc8;
    u16x8 a = *(const u16x8*)vsrc;
    u16x8 b2 = *(const u16x8*)(vsrc + 32);
    uint16_t* V0 = (uint16_t*)(smem + 16384);
#pragma unroll
    for (int e = 0; e < 8; ++e) {
      V0[(vc8 + e) * 72 + vrow] = a[e];
      V0[(vc8 + 32 + e) * 72 + vrow] = b2[e];
    }
  }
  __syncthreads();

  for (int t = 0; t < 64; ++t) {
    const int cur = t & 1;
    const uint16_t* Kc = (const uint16_t*)(smem + cur * 8192);
    const uint16_t* Vc = (const uint16_t*)(smem + 16384 + cur * 9216);
    // ---- prefetch next tile (K async->LDS, V ->regs) ----
    u16x8 va, vb2;
    if (t < 63) {
      const uint16_t* ksrc = kb + (size_t)(t + 1) * 64 * HDIM;
      uint16_t* Kn = (uint16_t*)(smem + (cur ^ 1) * 8192);
      gl_lds16(ksrc + koff, Kn + kdst);
      gl_lds16(ksrc + koff + 8 * HDIM, Kn + kdst + 8 * 64);
      const uint16_t* vsrc = vb + ((size_t)(t + 1) * 64 + vrow) * HDIM + vc8;
      va = *(const u16x8*)vsrc;
      vb2 = *(const u16x8*)(vsrc + 32);
    }

    // ---- S^T = K Q^T : sA = kv rows 0..31, sB = 32..63; col(lane&31) = q ----
    f32x16 sA, sB;
#pragma unroll
    for (int r = 0; r < 16; ++r) { sA[r] = 0.f; sB[r] = 0.f; }
#pragma unroll
    for (int ks = 0; ks < 4; ++ks) {
      int cc = ((ks * 2 + hi) ^ (q5 & 7)) * 8;
      bf16x8 kf0 = *(const bf16x8*)&Kc[q5 * 64 + cc];
      bf16x8 kf1 = *(const bf16x8*)&Kc[(32 + q5) * 64 + cc];
      sA = __builtin_amdgcn_mfma_f32_32x32x16_bf16(kf0, qf[ks], sA, 0, 0, 0);
      sB = __builtin_amdgcn_mfma_f32_32x32x16_bf16(kf1, qf[ks], sB, 0, 0, 0);
    }

    // ---- online softmax with defer-max (round-4 numerics) ----
    float pm = sA[0];
#pragma unroll
    for (int r = 1; r < 16; ++r) pm = fmaxf(pm, sA[r]);
#pragma unroll
    for (int r = 0; r < 16; ++r) pm = fmaxf(pm, sB[r]);
    pm = pairmax32(pm);
    if (__any(pm > m_run + 8.0f)) {  // defer-max (T13)
      float mn = fmaxf(m_run, pm);
      float c = __expf(m_run - mn);
      m_run = mn;
      l_run *= c;
#pragma unroll
      for (int db = 0; db < 2; ++db)
#pragma unroll
        for (int r = 0; r < 16; ++r) accO[db][r] *= c;
    }
    float lacc = 0.f;
#pragma unroll
    for (int r = 0; r < 16; ++r) {
      float ea = __expf(sA[r] - m_run);
      float eb = __expf(sB[r] - m_run);
      sA[r] = ea; sB[r] = eb;
      lacc += ea + eb;
    }
    l_run += lacc;  // lane-local partial; combined across hi-halves at the end

    // ---- P^T B-fragments: pack to bf16, redistribute halves (T12) ----
    bf16x8 pf[4];
    {
      uint32_t a0, a1, b0, b1;
      a0 = cvtpk(sA[0], sA[1]);  a1 = cvtpk(sA[2], sA[3]);
      b0 = cvtpk(sA[4], sA[5]);  b1 = cvtpk(sA[6], sA[7]);
      pls32(a0, b0); pls32(a1, b1);
      uint4 u = make_uint4(a0, a1, b0, b1);
      pf[0] = __builtin_bit_cast(bf16x8, u);
      a0 = cvtpk(sA[8], sA[9]);  a1 = cvtpk(sA[10], sA[11]);
      b0 = cvtpk(sA[12], sA[13]); b1 = cvtpk(sA[14], sA[15]);
      pls32(a0, b0); pls32(a1, b1);
      u = make_uint4(a0, a1, b0, b1);
      pf[1] = __builtin_bit_cast(bf16x8, u);
      a0 = cvtpk(sB[0], sB[1]);  a1 = cvtpk(sB[2], sB[3]);
      b0 = cvtpk(sB[4], sB[5]);  b1 = cvtpk(sB[6], sB[7]);
      pls32(a0, b0); pls32(a1, b1);
      u = make_uint4(a0, a1, b0, b1);
      pf[2] = __builtin_bit_cast(bf16x8, u);
      a0 = cvtpk(sB[8], sB[9]);  a1 = cvtpk(sB[10], sB[11]);
      b0 = cvtpk(sB[12], sB[13]); b1 = cvtpk(sB[14], sB[15]);
      pls32(a0, b0); pls32(a1, b1);
      u = make_uint4(a0, a1, b0, b1);
      pf[3] = __builtin_bit_cast(bf16x8, u);
    }

    // ---- O^T += V^T P^T ----
#pragma unroll
    for (int ksl = 0; ksl < 4; ++ksl) {
#pragma unroll
      for (int db = 0; db < 2; ++db) {
        bf16x8 vf = *(const bf16x8*)&Vc[(db * 32 + q5) * 72 + ksl * 16 + hi * 8];
        accO[db] = __builtin_amdgcn_mfma_f32_32x32x16_bf16(vf, pf[ksl], accO[db], 0, 0, 0);
      }
    }

    // ---- scatter prefetched V into next buffer (no one reads it yet) ----
    if (t < 63) {
      uint16_t* Vn = (uint16_t*)(smem + 16384 + (cur ^ 1) * 9216);
#pragma unroll
      for (int e = 0; e < 8; ++e) {
        Vn[(vc8 + e) * 72 + vrow] = va[e];
        Vn[(vc8 + 32 + e) * 72 + vrow] = vb2[e];
      }
    }
    __syncthreads();  // single barrier: cur fully read, nxt fully written
  }

  // ---- epilogue: combine l across hi-halves, transpose O^T through LDS ----
  float l_tot = l_run + __shfl_xor(l_run, 32);
  float inv = 1.0f / l_tot;
  __syncthreads();
  uint16_t* Epi = (uint16_t*)smem + wave * 2304;  // [32][72] per wave
#pragma unroll
  for (int db = 0; db < 2; ++db)
#pragma unroll
    for (int r = 0; r < 16; ++r) {
      int d = db * 32 + (r & 3) + 8 * (r >> 2) + 4 * hi;
      Epi[q5 * 72 + d] = f2bf(accO[db][r] * inv);
    }
  const int b = bh >> 4, h = bh & (NH - 1);
#pragma unroll
  for (int i = 0; i < 4; ++i) {
    int c = lane + i * 64;
    int row = c >> 3, off = (c & 7) * 8;
    u16x8 vv = *(const u16x8*)&Epi[row * 72 + off];
    int t = qt * 128 + wave * 32 + row;
    *(u16x8*)&yw[((size_t)b * TLEN + t) * DIMSZ + h * HDIM + off] = vv;
  }
}

// ---------------- launch ----------------
extern "C" void kernel_launch(void* const* d_in, const int* in_sizes, int n_in,
                              void* d_out, int out_size, void* d_ws, size_t ws_size,
                              hipStream_t stream) {
  const float* x = (const float*)d_in[0];
  const float* cosb = (const float*)d_in[1];
  const float* sinb = (const float*)d_in[2];
  const float* wq = (const float*)d_in[3];
  const float* wk = (const float*)d_in[4];
  const float* wv = (const float*)d_in[5];
  const float* wo = (const float*)d_in[6];
  float* out = (float*)d_out;

  char* w = (char*)d_ws;
  uint16_t* qh = (uint16_t*)w;    w += (size_t)BSZ * NH * TLEN * HDIM * 2;  // 32 MB
  uint16_t* kh = (uint16_t*)w;    w += (size_t)BSZ * NH * TLEN * HDIM * 2;  // 32 MB
  uint16_t* vh = (uint16_t*)w;    w += (size_t)BSZ * NH * TLEN * HDIM * 2;  // 32 MB
  uint16_t* xb = (uint16_t*)w;    w += (size_t)BSZ * TLEN * DIMSZ * 2;      // 32 MB (reused as y)
  uint16_t* wqkvb = (uint16_t*)w; w += (size_t)3 * DIMSZ * DIMSZ * 2;       // 6 MB
  uint16_t* wob = (uint16_t*)w;   w += (size_t)DIMSZ * DIMSZ * 2;           // 2 MB

  // casts to bf16
  cvt_f32_bf16<<<8192, 256, 0, stream>>>(x, xb, 2097152);
  cvt_f32_bf16<<<512, 256, 0, stream>>>(wq, wqkvb, 131072);
  cvt_f32_bf16<<<512, 256, 0, stream>>>(wk, wqkvb + DIMSZ * DIMSZ, 131072);
  cvt_f32_bf16<<<512, 256, 0, stream>>>(wv, wqkvb + 2 * DIMSZ * DIMSZ, 131072);
  cvt_f32_bf16<<<512, 256, 0, stream>>>(wo, wob, 131072);

  // fused QKV projection -> per-head layouts
  gemm_bt<1><<<dim3(24, 128), 256, 0, stream>>>(xb, wqkvb, nullptr, qh, kh, vh,
                                                BSZ * TLEN, 3 * DIMSZ, DIMSZ);
  // rope + rms-norm in place (q scaled by 0.125)
  rope_rms<<<65536, 256, 0, stream>>>(qh, kh, cosb, sinb);
  // attention -> y (bf16, [B][T][H*64]) into xb's space
  flash_attn<<<2048, 256, 0, stream>>>(qh, kh, vh, xb);
  // output projection -> fp32 d_out
  gemm_bt<0><<<dim3(8, 128), 256, 0, stream>>>(xb, wob, out, nullptr, nullptr, nullptr,
                                               BSZ * TLEN, DIMSZ, DIMSZ);
}

// Round 10
// 801.362 us; speedup vs baseline: 1.0102x; 1.0102x over previous
//
#include <hip/hip_runtime.h>
#include <cstdint>

#define DIMSZ 1024
#define NH 16
#define HDIM 64
#define TLEN 4096
#define BSZ 4
#define EPSF 1.1920928955078125e-07f
#define LOG2E 1.44269504f

typedef __bf16 bf16x8 __attribute__((ext_vector_type(8)));
typedef float f32x4 __attribute__((ext_vector_type(4)));
typedef float f32x16 __attribute__((ext_vector_type(16)));
typedef uint16_t u16x8 __attribute__((ext_vector_type(8)));

__device__ __forceinline__ uint16_t f2bf(float f) {
  uint32_t u = __builtin_bit_cast(uint32_t, f);
  u += 0x7FFFu + ((u >> 16) & 1u);
  return (uint16_t)(u >> 16);
}
__device__ __forceinline__ float bf2f(uint16_t b) {
  return __builtin_bit_cast(float, ((uint32_t)b) << 16);
}

// async global->LDS, 16B per lane; LDS dest = wave-uniform base + lane*16
__device__ __forceinline__ void gl_lds16(const uint16_t* g, uint16_t* l) {
  __builtin_amdgcn_global_load_lds(
      (__attribute__((address_space(1))) uint32_t*)(g),
      (__attribute__((address_space(3))) uint32_t*)(l), 16, 0, 0);
}

// pack two f32 -> two bf16 in one u32 (low = a, high = b)
__device__ __forceinline__ uint32_t cvtpk(float a, float b) {
  uint32_t r;
  asm("v_cvt_pk_bf16_f32 %0, %1, %2" : "=v"(r) : "v"(a), "v"(b));
  return r;
}
// swap upper-32-lanes of a with lower-32-lanes of b (both updated).
// NOTE: operands must hold DISTINCT values (distinct live registers).
__device__ __forceinline__ void pls32(uint32_t& a, uint32_t& b) {
  asm("v_permlane32_swap_b32 %0, %1" : "+v"(a), "+v"(b));
}
// cross-half pair reductions via shfl (safe: compiler-generated)
__device__ __forceinline__ float pairmax32(float x) {
  return fmaxf(x, __shfl_xor(x, 32));
}
__device__ __forceinline__ float exp2_hw(float x) {
  return __builtin_amdgcn_exp2f(x);
}

// ---------------- fp32 -> bf16 cast (8 elems/thread) ----------------
__global__ __launch_bounds__(256) void cvt_f32_bf16(const float* __restrict__ src,
                                                    uint16_t* __restrict__ dst, int n8) {
  int i = blockIdx.x * 256 + threadIdx.x;
  if (i >= n8) return;
  const float4* s4 = ((const float4*)src) + (size_t)i * 2;
  float4 a = s4[0], b = s4[1];
  u16x8 o;
  o[0] = f2bf(a.x); o[1] = f2bf(a.y); o[2] = f2bf(a.z); o[3] = f2bf(a.w);
  o[4] = f2bf(b.x); o[5] = f2bf(b.y); o[6] = f2bf(b.z); o[7] = f2bf(b.w);
  *(((u16x8*)dst) + i) = o;
}

// ---------------- bf16 GEMM, C = A * W^T  (both row-major [.][K]) ----------------
// EPI=0: C fp32 [M][N].  EPI=1: scatter bf16 into q/k/v [B][H][T][64] layouts.
template <int EPI>
__global__ __launch_bounds__(256) void gemm_bt(const uint16_t* __restrict__ A,
                                               const uint16_t* __restrict__ Bw,
                                               float* __restrict__ C,
                                               uint16_t* __restrict__ q_out,
                                               uint16_t* __restrict__ k_out,
                                               uint16_t* __restrict__ v_out,
                                               int M, int N, int K) {
  __shared__ uint16_t As[128 * 32];
  __shared__ uint16_t Bs[128 * 32];
  const int nb = blockIdx.x, mb = blockIdx.y;
  const int tid = threadIdx.x;
  const int wave = tid >> 6, lane = tid & 63;
  const int l15 = lane & 15, l4 = lane >> 4;
  const int wr = wave >> 1, wc = wave & 1;

  f32x4 acc[4][4];
  const f32x4 fz = {0.f, 0.f, 0.f, 0.f};
#pragma unroll
  for (int i = 0; i < 4; ++i)
#pragma unroll
    for (int j = 0; j < 4; ++j) acc[i][j] = fz;

  const uint16_t* Ab = A + (size_t)mb * 128 * K;
  const uint16_t* Bb = Bw + (size_t)nb * 128 * K;
  const int rA = wave * 32 + (lane >> 2);
  const int cA = (lane & 3) * 8;

  for (int k0 = 0; k0 < K; k0 += 32) {
    gl_lds16(Ab + (size_t)rA * K + k0 + cA, &As[(wave * 32) * 32]);
    gl_lds16(Ab + (size_t)(rA + 16) * K + k0 + cA, &As[(wave * 32 + 16) * 32]);
    gl_lds16(Bb + (size_t)rA * K + k0 + cA, &Bs[(wave * 32) * 32]);
    gl_lds16(Bb + (size_t)(rA + 16) * K + k0 + cA, &Bs[(wave * 32 + 16) * 32]);
    __syncthreads();
    bf16x8 af[4], bfr[4];
#pragma unroll
    for (int i = 0; i < 4; ++i)
      af[i] = *(const bf16x8*)&As[(wr * 64 + i * 16 + l15) * 32 + l4 * 8];
#pragma unroll
    for (int j = 0; j < 4; ++j)
      bfr[j] = *(const bf16x8*)&Bs[(wc * 64 + j * 16 + l15) * 32 + l4 * 8];
#pragma unroll
    for (int i = 0; i < 4; ++i)
#pragma unroll
      for (int j = 0; j < 4; ++j)
        acc[i][j] = __builtin_amdgcn_mfma_f32_16x16x32_bf16(af[i], bfr[j], acc[i][j], 0, 0, 0);
    __syncthreads();
  }

  const int mrow = mb * 128 + wr * 64;
  const int ncol = nb * 128 + wc * 64;
  if (EPI == 0) {
#pragma unroll
    for (int i = 0; i < 4; ++i)
#pragma unroll
      for (int j = 0; j < 4; ++j) {
        int n = ncol + j * 16 + l15;
#pragma unroll
        for (int r = 0; r < 4; ++r) {
          int m = mrow + i * 16 + l4 * 4 + r;
          C[(size_t)m * N + n] = acc[i][j][r];
        }
      }
  } else {
#pragma unroll
    for (int i = 0; i < 4; ++i)
#pragma unroll
      for (int j = 0; j < 4; ++j) {
        int n = ncol + j * 16 + l15;
        int tens = n >> 10;
        int h = (n >> 6) & (NH - 1);
        int d = n & (HDIM - 1);
        uint16_t* dst = (tens == 0) ? q_out : ((tens == 1) ? k_out : v_out);
#pragma unroll
        for (int r = 0; r < 4; ++r) {
          int m = mrow + i * 16 + l4 * 4 + r;
          int b = m >> 12, t = m & (TLEN - 1);
          dst[((((size_t)b * NH + h) * TLEN) + t) * HDIM + d] = f2bf(acc[i][j][r]);
        }
      }
  }
}

// ---------------- RoPE + RMS-norm, in place on q/k [B][H][T][64] ----------------
// q additionally scaled by 1/sqrt(HD)=0.125
__global__ __launch_bounds__(256) void rope_rms(uint16_t* __restrict__ qh,
                                                uint16_t* __restrict__ kh,
                                                const float* __restrict__ cosb,
                                                const float* __restrict__ sinb) {
  const int wid = blockIdx.x * 4 + (threadIdx.x >> 6);
  const int lane = threadIdx.x & 63;
  const int t = wid & (TLEN - 1);
  const int p = lane & 31;
  const float c = cosb[t * 32 + p];
  const float s = sinb[t * 32 + p];
  const size_t base = (size_t)wid * HDIM;
  {
    float v = bf2f(qh[base + lane]);
    float x1 = __shfl(v, p);
    float x2 = __shfl(v, p + 32);
    float rot = (lane < 32) ? (x1 * c + x2 * s) : (x2 * c - x1 * s);
    float ss = rot * rot;
#pragma unroll
    for (int off = 1; off < 64; off <<= 1) ss += __shfl_xor(ss, off);
    float sc = rsqrtf(ss * (1.0f / HDIM) + EPSF) * 0.125f;
    qh[base + lane] = f2bf(rot * sc);
  }
  {
    float v = bf2f(kh[base + lane]);
    float x1 = __shfl(v, p);
    float x2 = __shfl(v, p + 32);
    float rot = (lane < 32) ? (x1 * c + x2 * s) : (x2 * c - x1 * s);
    float ss = rot * rot;
#pragma unroll
    for (int off = 1; off < 64; off <<= 1) ss += __shfl_xor(ss, off);
    kh[base + lane] = f2bf(rot * rsqrtf(ss * (1.0f / HDIM) + EPSF));
  }
}

// ---------------- flash attention fwd ----------------
// Round-7 verified structure: swapped QK^T (S^T = K Q^T), in-register online
// softmax (max-tracked, defer-max THR=8), single barrier per KV tile,
// double-buffered K (global_load_lds) and V (reg-staged transpose).
// Round-9 deltas (lane-local VALU only): exp2(fma) softmax, max3 fmax tree.
__global__ __launch_bounds__(256) void flash_attn(const uint16_t* __restrict__ qh,
                                                  const uint16_t* __restrict__ kh,
                                                  const uint16_t* __restrict__ vh,
                                                  uint16_t* __restrict__ yw) {
  __shared__ __align__(16) char smem[34816];
  // layout: K0 [0,8192) K1 [8192,16384) V0 [16384,25600) V1 [25600,34816)

  const int braw = blockIdx.x;
  const int bid = (braw & 7) * 256 + (braw >> 3);  // XCD swizzle (2048 % 8 == 0)
  const int qt = bid & 31;      // 32 q-tiles of 128
  const int bh = bid >> 5;      // b*NH + h
  const int tid = threadIdx.x;
  const int wave = tid >> 6, lane = tid & 63;
  const int q5 = lane & 31, hi = lane >> 5;

  // Q^T B-fragments in registers: lane holds Q[q5][ks*16 + hi*8 + 0..7]
  const uint16_t* qb = qh + ((size_t)bh * TLEN + qt * 128 + wave * 32) * HDIM;
  bf16x8 qf[4];
#pragma unroll
  for (int ks = 0; ks < 4; ++ks)
    qf[ks] = *(const bf16x8*)(qb + q5 * HDIM + ks * 16 + hi * 8);

  const uint16_t* kb = kh + (size_t)bh * TLEN * HDIM;
  const uint16_t* vb = vh + (size_t)bh * TLEN * HDIM;

  // K staging: wave stages rows [wave*16, +16), src chunk pre-swizzled
  const int krow = wave * 16 + (lane >> 3);
  const int kc8 = (lane & 7) ^ (krow & 7);
  const size_t koff = (size_t)krow * HDIM + kc8 * 8;
  const int kdst = wave * 16 * 64;

  // V staging: thread owns (row=tid&63, colblocks vc8 and vc8+32)
  const int vrow = tid & 63;
  const int vc8 = (tid >> 6) * 8;

  f32x16 accO[2];
  float m_run = -INFINITY, l_run = 0.f;
#pragma unroll
  for (int db = 0; db < 2; ++db)
#pragma unroll
    for (int r = 0; r < 16; ++r) accO[db][r] = 0.f;

  // ---- prologue: stage tile 0 into buffer 0 ----
  gl_lds16(kb + koff, (uint16_t*)smem + kdst);
  gl_lds16(kb + koff + 8 * HDIM, (uint16_t*)smem + kdst + 8 * 64);
  {
    const uint16_t* vsrc = vb + (size_t)vrow * HDIM + vc8;
    u16x8 a = *(const u16x8*)vsrc;
    u16x8 b2 = *(const u16x8*)(vsrc + 32);
    uint16_t* V0 = (uint16_t*)(smem + 16384);
#pragma unroll
    for (int e = 0; e < 8; ++e) {
      V0[(vc8 + e) * 72 + vrow] = a[e];
      V0[(vc8 + 32 + e) * 72 + vrow] = b2[e];
    }
  }
  __syncthreads();

  for (int t = 0; t < 64; ++t) {
    const int cur = t & 1;
    const uint16_t* Kc = (const uint16_t*)(smem + cur * 8192);
    const uint16_t* Vc = (const uint16_t*)(smem + 16384 + cur * 9216);
    // ---- prefetch next tile (K async->LDS, V ->regs) ----
    u16x8 va, vb2;
    if (t < 63) {
      const uint16_t* ksrc = kb + (size_t)(t + 1) * 64 * HDIM;
      uint16_t* Kn = (uint16_t*)(smem + (cur ^ 1) * 8192);
      gl_lds16(ksrc + koff, Kn + kdst);
      gl_lds16(ksrc + koff + 8 * HDIM, Kn + kdst + 8 * 64);
      const uint16_t* vsrc = vb + ((size_t)(t + 1) * 64 + vrow) * HDIM + vc8;
      va = *(const u16x8*)vsrc;
      vb2 = *(const u16x8*)(vsrc + 32);
    }

    // ---- S^T = K Q^T : sA = kv rows 0..31, sB = 32..63; col(lane&31) = q ----
    f32x16 sA, sB;
#pragma unroll
    for (int r = 0; r < 16; ++r) { sA[r] = 0.f; sB[r] = 0.f; }
#pragma unroll
    for (int ks = 0; ks < 4; ++ks) {
      int cc = ((ks * 2 + hi) ^ (q5 & 7)) * 8;
      bf16x8 kf0 = *(const bf16x8*)&Kc[q5 * 64 + cc];
      bf16x8 kf1 = *(const bf16x8*)&Kc[(32 + q5) * 64 + cc];
      sA = __builtin_amdgcn_mfma_f32_32x32x16_bf16(kf0, qf[ks], sA, 0, 0, 0);
      sB = __builtin_amdgcn_mfma_f32_32x32x16_bf16(kf1, qf[ks], sB, 0, 0, 0);
    }

    // ---- online softmax with defer-max (max3-fusable tree, exp2 fma) ----
    float pm = fmaxf(sA[0], sA[1]);
#pragma unroll
    for (int r = 2; r < 16; r += 2) pm = fmaxf(fmaxf(pm, sA[r]), sA[r + 1]);
#pragma unroll
    for (int r = 0; r < 16; r += 2) pm = fmaxf(fmaxf(pm, sB[r]), sB[r + 1]);
    pm = pairmax32(pm);
    if (__any(pm > m_run + 8.0f)) {  // defer-max (T13)
      float mn = fmaxf(m_run, pm);
      float c = exp2_hw((m_run - mn) * LOG2E);
      m_run = mn;
      l_run *= c;
#pragma unroll
      for (int db = 0; db < 2; ++db)
#pragma unroll
        for (int r = 0; r < 16; ++r) accO[db][r] *= c;
    }
    const float mneg = -m_run * LOG2E;
    float lacc = 0.f;
#pragma unroll
    for (int r = 0; r < 16; ++r) {
      float ea = exp2_hw(fmaf(sA[r], LOG2E, mneg));
      float eb = exp2_hw(fmaf(sB[r], LOG2E, mneg));
      sA[r] = ea; sB[r] = eb;
      lacc += ea + eb;
    }
    l_run += lacc;  // lane-local partial; combined across hi-halves at the end

    // ---- P^T B-fragments: pack to bf16, redistribute halves (T12) ----
    bf16x8 pf[4];
    {
      uint32_t a0, a1, b0, b1;
      a0 = cvtpk(sA[0], sA[1]);  a1 = cvtpk(sA[2], sA[3]);
      b0 = cvtpk(sA[4], sA[5]);  b1 = cvtpk(sA[6], sA[7]);
      pls32(a0, b0); pls32(a1, b1);
      uint4 u = make_uint4(a0, a1, b0, b1);
      pf[0] = __builtin_bit_cast(bf16x8, u);
      a0 = cvtpk(sA[8], sA[9]);  a1 = cvtpk(sA[10], sA[11]);
      b0 = cvtpk(sA[12], sA[13]); b1 = cvtpk(sA[14], sA[15]);
      pls32(a0, b0); pls32(a1, b1);
      u = make_uint4(a0, a1, b0, b1);
      pf[1] = __builtin_bit_cast(bf16x8, u);
      a0 = cvtpk(sB[0], sB[1]);  a1 = cvtpk(sB[2], sB[3]);
      b0 = cvtpk(sB[4], sB[5]);  b1 = cvtpk(sB[6], sB[7]);
      pls32(a0, b0); pls32(a1, b1);
      u = make_uint4(a0, a1, b0, b1);
      pf[2] = __builtin_bit_cast(bf16x8, u);
      a0 = cvtpk(sB[8], sB[9]);  a1 = cvtpk(sB[10], sB[11]);
      b0 = cvtpk(sB[12], sB[13]); b1 = cvtpk(sB[14], sB[15]);
      pls32(a0, b0); pls32(a1, b1);
      u = make_uint4(a0, a1, b0, b1);
      pf[3] = __builtin_bit_cast(bf16x8, u);
    }

    // ---- O^T += V^T P^T ----
#pragma unroll
    for (int ksl = 0; ksl < 4; ++ksl) {
#pragma unroll
      for (int db = 0; db < 2; ++db) {
        bf16x8 vf = *(const bf16x8*)&Vc[(db * 32 + q5) * 72 + ksl * 16 + hi * 8];
        accO[db] = __builtin_amdgcn_mfma_f32_32x32x16_bf16(vf, pf[ksl], accO[db], 0, 0, 0);
      }
    }

    // ---- scatter prefetched V into next buffer (no one reads it yet) ----
    if (t < 63) {
      uint16_t* Vn = (uint16_t*)(smem + 16384 + (cur ^ 1) * 9216);
#pragma unroll
      for (int e = 0; e < 8; ++e) {
        Vn[(vc8 + e) * 72 + vrow] = va[e];
        Vn[(vc8 + 32 + e) * 72 + vrow] = vb2[e];
      }
    }
    __syncthreads();  // single barrier: cur fully read, nxt fully written
  }

  // ---- epilogue: combine l across hi-halves, transpose O^T through LDS ----
  float l_tot = l_run + __shfl_xor(l_run, 32);
  float inv = 1.0f / l_tot;
  __syncthreads();
  uint16_t* Epi = (uint16_t*)smem + wave * 2304;  // [32][72] per wave
#pragma unroll
  for (int db = 0; db < 2; ++db)
#pragma unroll
    for (int r = 0; r < 16; ++r) {
      int d = db * 32 + (r & 3) + 8 * (r >> 2) + 4 * hi;
      Epi[q5 * 72 + d] = f2bf(accO[db][r] * inv);
    }
  const int b = bh >> 4, h = bh & (NH - 1);
#pragma unroll
  for (int i = 0; i < 4; ++i) {
    int c = lane + i * 64;
    int row = c >> 3, off = (c & 7) * 8;
    u16x8 vv = *(const u16x8*)&Epi[row * 72 + off];
    int t = qt * 128 + wave * 32 + row;
    *(u16x8*)&yw[((size_t)b * TLEN + t) * DIMSZ + h * HDIM + off] = vv;
  }
}

// ---------------- launch ----------------
extern "C" void kernel_launch(void* const* d_in, const int* in_sizes, int n_in,
                              void* d_out, int out_size, void* d_ws, size_t ws_size,
                              hipStream_t stream) {
  const float* x = (const float*)d_in[0];
  const float* cosb = (const float*)d_in[1];
  const float* sinb = (const float*)d_in[2];
  const float* wq = (const float*)d_in[3];
  const float* wk = (const float*)d_in[4];
  const float* wv = (const float*)d_in[5];
  const float* wo = (const float*)d_in[6];
  float* out = (float*)d_out;

  char* w = (char*)d_ws;
  uint16_t* qh = (uint16_t*)w;    w += (size_t)BSZ * NH * TLEN * HDIM * 2;  // 32 MB
  uint16_t* kh = (uint16_t*)w;    w += (size_t)BSZ * NH * TLEN * HDIM * 2;  // 32 MB
  uint16_t* vh = (uint16_t*)w;    w += (size_t)BSZ * NH * TLEN * HDIM * 2;  // 32 MB
  uint16_t* xb = (uint16_t*)w;    w += (size_t)BSZ * TLEN * DIMSZ * 2;      // 32 MB (reused as y)
  uint16_t* wqkvb = (uint16_t*)w; w += (size_t)3 * DIMSZ * DIMSZ * 2;       // 6 MB
  uint16_t* wob = (uint16_t*)w;   w += (size_t)DIMSZ * DIMSZ * 2;           // 2 MB

  // casts to bf16
  cvt_f32_bf16<<<8192, 256, 0, stream>>>(x, xb, 2097152);
  cvt_f32_bf16<<<512, 256, 0, stream>>>(wq, wqkvb, 131072);
  cvt_f32_bf16<<<512, 256, 0, stream>>>(wk, wqkvb + DIMSZ * DIMSZ, 131072);
  cvt_f32_bf16<<<512, 256, 0, stream>>>(wv, wqkvb + 2 * DIMSZ * DIMSZ, 131072);
  cvt_f32_bf16<<<512, 256, 0, stream>>>(wo, wob, 131072);

  // fused QKV projection -> per-head layouts
  gemm_bt<1><<<dim3(24, 128), 256, 0, stream>>>(xb, wqkvb, nullptr, qh, kh, vh,
                                                BSZ * TLEN, 3 * DIMSZ, DIMSZ);
  // rope + rms-norm in place (q scaled by 0.125)
  rope_rms<<<65536, 256, 0, stream>>>(qh, kh, cosb, sinb);
  // attention -> y (bf16, [B][T][H*64]) into xb's space
  flash_attn<<<2048, 256, 0, stream>>>(qh, kh, vh, xb);
  // output projection -> fp32 d_out
  gemm_bt<0><<<dim3(8, 128), 256, 0, stream>>>(xb, wob, out, nullptr, nullptr, nullptr,
                                               BSZ * TLEN, DIMSZ, DIMSZ);
}